// Round 10
// baseline (1129.232 us; speedup 1.0000x reference)
//
#include <hip/hip_runtime.h>
#include <hip/hip_bf16.h>
#include <math.h>

// Problem constants (fixed by the reference: H=2048, V=32000, B=8, T=256, G=4).
#define H_DIM 2048
#define V_DIM 32000
#define BT    2048            // B*T rows
#define BETA  0.1f
#define EPSR  1e-4f

// ---- fast-path GEMM geometry: 256x256 tile, BK=64, 8 waves (2M x 4N) ----
#define NT    32              // K tiles of 64 (H/64)
#define NBLK2 125             // V / 256
// ---- fallback geometry (round-1 kernel, unchanged) ----
#define TM 128
#define TN 128
#define TK 32
#define NBLK_FB 250

typedef __attribute__((ext_vector_type(8))) short bf16x8;   // 8 bf16 = 4 VGPRs
typedef __attribute__((ext_vector_type(4))) float f32x4;

// ---------------- helpers ----------------

// Pack two fp32 -> bf16x2 (round-half-up via +0x8000, take high 16 bits each).
__device__ __forceinline__ unsigned pack_bf16x2(float a, float b) {
    unsigned ua = __float_as_uint(a) + 0x8000u;
    unsigned ub = __float_as_uint(b) + 0x8000u;
    return __builtin_amdgcn_perm(ub, ua, 0x07060302u);
}

__device__ __forceinline__ void merge_ms(float& m, float& s, float m2, float s2) {
    float nm = fmaxf(m, m2);
    s = s * __expf(m - nm) + s2 * __expf(m2 - nm);
    m = nm;
}

// Async global->LDS, 16 B per lane. LDS dest = wave-uniform base + lane*16.
__device__ __forceinline__ void gl_lds16(const void* g, void* l) {
    __builtin_amdgcn_global_load_lds(
        (const __attribute__((address_space(1))) void*)g,
        (__attribute__((address_space(3))) void*)l, 16, 0, 0);
}

// ---------------- linear pack: fp32 [R,2048] -> bf16 slabs per (256-row, 64-K) tile --------
// Slab (rt,kt) is 32 KB: chunk (kk*256+row) holds src[rt*256+row][kt*64+kk*8..+8] as 8 bf16.
// 512 threads/block; reads fully linear (16 rows x 8KB contiguous); writes 256B segments.
#define PROWS 16

__device__ __forceinline__ void pack_rows(
    const float* __restrict__ src, uint4* __restrict__ dst, int rb, int t,
    ushort (*tile)[2056])
{
    const int r0    = rb * PROWS;          // first global row of this block
    const int rt    = r0 >> 8;             // slab row-tile (256-row units)
    const int rbase = r0 & 255;            // row offset within the slab

    const float4* s4 = (const float4*)(src + (size_t)r0 * H_DIM);
    #pragma unroll
    for (int i = 0; i < PROWS; i++) {
        float4 v = s4[i * 512 + t];
        uint2 b;
        b.x = pack_bf16x2(v.x, v.y);
        b.y = pack_bf16x2(v.z, v.w);
        *(uint2*)&tile[i][t * 4] = b;                  // 8B store
    }
    __syncthreads();

    #pragma unroll
    for (int i = 0; i < 8; i++) {
        int c   = i * 512 + t;                         // 0..4095
        int kt  = c >> 7, kk = (c >> 4) & 7, row = c & 15;
        uint4 v = *(const uint4*)&tile[row][kt * 64 + kk * 8];
        dst[(((size_t)rt * NT + kt) << 11) + kk * 256 + rbase + row] = v;
    }
}

// Activations: x (blocks 0..127) and rx (blocks 128..255).
__global__ __launch_bounds__(512) void pack_act_kernel(
    const float* __restrict__ x, const float* __restrict__ rx,
    uint4* __restrict__ Ap, uint4* __restrict__ Rp)
{
    __shared__ __align__(16) ushort tile[PROWS][2056];   // 65,792 B -> 2 blocks/CU
    const int bx = blockIdx.x;
    if (bx < 128) pack_rows(x,  Ap, bx,       threadIdx.x, tile);
    else          pack_rows(rx, Rp, bx - 128, threadIdx.x, tile);
}

// One weight matrix -> the SHARED weight slab buffer (called twice, stream-serialized
// around gemm1 so w's slabs are consumed before rw overwrites them).
__global__ __launch_bounds__(512) void pack_w_kernel(
    const float* __restrict__ src, uint4* __restrict__ dst)
{
    __shared__ __align__(16) ushort tile[PROWS][2056];
    pack_rows(src, dst, blockIdx.x, threadIdx.x, tile);
}

// ---------------- 256^2 merged-phase GEMM v10 (2 MPs per K-tile) ----------------
// One dispatch per model, grid 1000. Work index l = (bid%8)*125 + bid/8; mb = l&7 fastest:
// 8 co-resident same-XCD blocks share one B-panel (L2-served; proven R3).
//
// v10: phase granularity halved -- 2 merged phases per K-tile (3 barriers/tile vs 5).
// MP1(X): read B(X) all 8 + A F0-F3 (8), stage next-tile.ht3 -> other buf, 32 MFMA, bar.
// MP2(X): read A F4-F7 (8), stage nextnext.ht0-2 -> X, vmcnt(6)+pub-bar, 32 MFMA, bar.
// Ledger: MP1 +2 loads, MP2 +6; at MP2's vmcnt point outstanding=14, keep 6 newest
// (nextnext.ht0-2) -> next tile fully drained. Hazards: MP2's stages into X target
// {B, A-F0-F3} regions sealed by MP1(X)'s barrier; MP1's ht3->Y sealed by prev MP2's
// barrier; MP2's own reads (F4-F7) disjoint from its stage targets. Tail dummies
// (clamped index) rewrite identical data.
// Epilogue v8 (slim): exact max/argmax reduce, then one exp pass + sum reduce.

#define MF(a,b,c) __builtin_amdgcn_mfma_f32_16x16x32_bf16(a, b, c, 0, 0, 0)

#define LDA(dst, BUF, F, KS) \
    dst = *(const bf16x8*)(smem + (BUF)*65536 + (KS)*16384 + (F)*256 + aoff)
#define LDB(dst, BUF, CF, KS) \
    dst = *(const bf16x8*)(smem + (BUF)*65536 + (KS)*16384 + (CF)*256 + boff)

#define STAGE(SG, SHT, SBUF) do { \
    const char* s_ = ((SHT) < 2 ? Bbase : Abase) + ((size_t)(SG) << 15); \
    char* l_ = smem + (SBUF)*65536 + ((SHT) < 2 ? 32768 : 0); \
    gl_lds16(s_ + soff[SHT][0], l_ + soff[SHT][0]); \
    gl_lds16(s_ + soff[SHT][1], l_ + soff[SHT][1]); \
} while (0)

#define MFMA_PH(F0, A0, A1, A2, A3) do { \
    acc[F0][0]   = MF(A0, bfr[0][0], acc[F0][0]); \
    acc[F0][1]   = MF(A0, bfr[1][0], acc[F0][1]); \
    acc[F0][2]   = MF(A0, bfr[2][0], acc[F0][2]); \
    acc[F0][3]   = MF(A0, bfr[3][0], acc[F0][3]); \
    acc[F0+1][0] = MF(A2, bfr[0][0], acc[F0+1][0]); \
    acc[F0+1][1] = MF(A2, bfr[1][0], acc[F0+1][1]); \
    acc[F0+1][2] = MF(A2, bfr[2][0], acc[F0+1][2]); \
    acc[F0+1][3] = MF(A2, bfr[3][0], acc[F0+1][3]); \
    acc[F0][0]   = MF(A1, bfr[0][1], acc[F0][0]); \
    acc[F0][1]   = MF(A1, bfr[1][1], acc[F0][1]); \
    acc[F0][2]   = MF(A1, bfr[2][1], acc[F0][2]); \
    acc[F0][3]   = MF(A1, bfr[3][1], acc[F0][3]); \
    acc[F0+1][0] = MF(A3, bfr[0][1], acc[F0+1][0]); \
    acc[F0+1][1] = MF(A3, bfr[1][1], acc[F0+1][1]); \
    acc[F0+1][2] = MF(A3, bfr[2][1], acc[F0+1][2]); \
    acc[F0+1][3] = MF(A3, bfr[3][1], acc[F0+1][3]); \
} while (0)

// Merged phase 1 of tile in BUF: B + F0-F3; stage SG1.ht3 -> other buffer.
#define MP1(BUF, SG1) do { \
    bf16x8 a0_, a1_, a2_, a3_, a4_, a5_, a6_, a7_; \
    LDB(bfr[0][0], BUF, 0, 0); LDB(bfr[0][1], BUF, 0, 1); \
    LDB(bfr[1][0], BUF, 1, 0); LDB(bfr[1][1], BUF, 1, 1); \
    LDB(bfr[2][0], BUF, 2, 0); LDB(bfr[2][1], BUF, 2, 1); \
    LDB(bfr[3][0], BUF, 3, 0); LDB(bfr[3][1], BUF, 3, 1); \
    LDA(a0_, BUF, 0, 0); LDA(a1_, BUF, 0, 1); \
    LDA(a2_, BUF, 1, 0); LDA(a3_, BUF, 1, 1); \
    LDA(a4_, BUF, 2, 0); LDA(a5_, BUF, 2, 1); \
    LDA(a6_, BUF, 3, 0); LDA(a7_, BUF, 3, 1); \
    STAGE(SG1, 3, (BUF) ^ 1); \
    __builtin_amdgcn_s_setprio(1); \
    MFMA_PH(0, a0_, a1_, a2_, a3_); \
    MFMA_PH(2, a4_, a5_, a6_, a7_); \
    __builtin_amdgcn_s_setprio(0); \
    asm volatile("" ::: "memory"); \
    __builtin_amdgcn_s_barrier(); \
    asm volatile("" ::: "memory"); \
} while (0)

// Merged phase 2 of tile in BUF: F4-F7; stage SG2.ht0-2 -> BUF; counted drain + publish.
#define MP2(BUF, SG2) do { \
    bf16x8 a0_, a1_, a2_, a3_, a4_, a5_, a6_, a7_; \
    LDA(a0_, BUF, 4, 0); LDA(a1_, BUF, 4, 1); \
    LDA(a2_, BUF, 5, 0); LDA(a3_, BUF, 5, 1); \
    LDA(a4_, BUF, 6, 0); LDA(a5_, BUF, 6, 1); \
    LDA(a6_, BUF, 7, 0); LDA(a7_, BUF, 7, 1); \
    STAGE(SG2, 0, BUF); STAGE(SG2, 1, BUF); STAGE(SG2, 2, BUF); \
    asm volatile("s_waitcnt vmcnt(6)" ::: "memory"); \
    __builtin_amdgcn_s_barrier(); \
    asm volatile("" ::: "memory"); \
    __builtin_amdgcn_s_setprio(1); \
    MFMA_PH(4, a0_, a1_, a2_, a3_); \
    MFMA_PH(6, a4_, a5_, a6_, a7_); \
    __builtin_amdgcn_s_setprio(0); \
    asm volatile("" ::: "memory"); \
    __builtin_amdgcn_s_barrier(); \
    asm volatile("" ::: "memory"); \
} while (0)

__global__ __launch_bounds__(512, 2) void gemm_lse_v10(
    const ushort* __restrict__ Apk, const ushort* __restrict__ Bpk,
    float4* __restrict__ pp)
{
    __shared__ __align__(16) char smem_raw[131072 + 12288];  // tiles | epilogue scratch
    char* smem = smem_raw;
    float* redM = (float*)(smem_raw + 131072);               // 256 rows x 4 wn-segments
    float* redS = (float*)(smem_raw + 131072 + 4096);
    int*   redC = (int*)  (smem_raw + 131072 + 8192);

    const int tid  = threadIdx.x;
    const int lane = tid & 63;
    const int wv   = tid >> 6;                          // 0..7
    const int wm   = wv >> 2, wn = wv & 3;              // 2 x 4 wave grid: 128x64 per wave
    const int q    = lane >> 4, cl = lane & 15;

    // XCD-chunked work mapping: bid%8 ~ XCD (dispatch round-robin heuristic; speed-only).
    const int bid = blockIdx.x;                         // 0..999
    const int l   = (bid & 7) * 125 + (bid >> 3);       // bijective (1000 = 8*125)
    const int mb  = l & 7;                              // varies fastest: 8 blocks share panel
    const int nb  = l >> 3;                             // 0..124 = B-panel

    const char* Abase = (const char*)Apk + ((size_t)(mb * NT) << 15);
    const char* Bbase = (const char*)Bpk + ((size_t)(nb * NT) << 15);

    // Fragment-read base offsets (within a 64 KB tile-buffer).
    const int aoff = q * 4096 + (wm * 128 + cl) * 16;
    const int boff = 32768 + q * 4096 + (wn * 64 + cl) * 16;

    // Staging offsets: chunk c = wv*2 + li covers (kk, row-group), 64 rows/lane.
    int soff[4][2];
    #pragma unroll
    for (int li = 0; li < 2; li++) {
        int c = wv * 2 + li;
        int kko = (((c >> 3) << 2) + ((c >> 1) & 3)) * 4096;
        int rg = c & 1;
        soff[0][li] = kko + (rg * 64 + lane) * 16;            // B rows 0..128
        soff[1][li] = kko + (128 + rg * 64 + lane) * 16;      // B rows 128..256
        soff[2][li] = kko + (rg * 128 + lane) * 16;           // A rows {0-64, 128-192}
        soff[3][li] = kko + (rg * 128 + 64 + lane) * 16;      // A rows {64-128, 192-256}
    }

    f32x4 acc[8][4];
    const f32x4 zero = {0.f, 0.f, 0.f, 0.f};
    #pragma unroll
    for (int i = 0; i < 8; i++)
        #pragma unroll
        for (int j = 0; j < 4; j++) acc[i][j] = zero;

    bf16x8 bfr[4][2];

    // Prologue: tile0 (4 HTs) -> buf0, tile1 (ht0..2) -> buf1; 14 loads, keep 6 in flight.
    STAGE(0, 0, 0); STAGE(0, 1, 0); STAGE(0, 2, 0); STAGE(0, 3, 0);
    STAGE(1, 0, 1); STAGE(1, 1, 1); STAGE(1, 2, 1);
    asm volatile("s_waitcnt vmcnt(6)" ::: "memory");
    __builtin_amdgcn_s_barrier();
    asm volatile("" ::: "memory");

    #pragma unroll 1
    for (int ii = 0; ii < 16; ii++) {
        int t1 = 2 * ii + 1;                                // <= 31, always real
        int t2 = 2 * ii + 2; if (t2 > NT - 1) t2 = NT - 1;  // tail: dummy (valid) stages,
        int t3 = 2 * ii + 3; if (t3 > NT - 1) t3 = NT - 1;  // keeps the vmcnt ledger exact
        MP1(0, t1);       // tile 2ii   (buf0): B+F0-3; stage t1.ht3 -> buf1
        MP2(0, t2);       //                    F4-7;   stage t2.ht0-2 -> buf0; vmcnt(6)
        MP1(1, t2);       // tile 2ii+1 (buf1): B+F0-3; stage t2.ht3 -> buf0
        MP2(1, t3);       //                    F4-7;   stage t3.ht0-2 -> buf1; vmcnt(6)
    }

    // ---- epilogue v8: exact max/argmax reduce, then one exp pass + sum reduce ----
    // C layout (m89): col = cf*16 + cl (+ wn*64), row = f*16 + q*4 + reg (+ wm*128).
    #pragma unroll
    for (int f = 0; f < 8; f++) {
        #pragma unroll
        for (int r = 0; r < 4; r++) {
            float v0 = acc[f][0][r], v1 = acc[f][1][r], v2 = acc[f][2][r], v3 = acc[f][3][r];
            // within-lane max/argmax over the 4 col-frags (ascending cols; > keeps lowest)
            float m = v0; int cj = 0;
            if (v1 > m) { m = v1; cj = 1; }
            if (v2 > m) { m = v2; cj = 2; }
            if (v3 > m) { m = v3; cj = 3; }
            int cidx = wn * 64 + cj * 16 + cl;
            // exact 16-lane max/argmax reduce (no expf)
            #pragma unroll
            for (int off = 1; off < 16; off <<= 1) {
                float m2 = __shfl_xor(m, off);
                int   c2 = __shfl_xor(cidx, off);
                if (m2 > m || (m2 == m && c2 < cidx)) cidx = c2;   // first-occurrence ties
                m = fmaxf(m, m2);
            }
            // all 16 lanes now hold the segment max; one exp pass + sum reduce
            float s = __expf(v0 - m) + __expf(v1 - m) + __expf(v2 - m) + __expf(v3 - m);
            #pragma unroll
            for (int off = 1; off < 16; off <<= 1) s += __shfl_xor(s, off);
            int rloc = wm * 128 + f * 16 + q * 4 + r;
            if (cl == 0) { redM[rloc*4+wn] = m; redS[rloc*4+wn] = s; redC[rloc*4+wn] = cidx; }
        }
    }
    asm volatile("s_waitcnt lgkmcnt(0)" ::: "memory");   // seal scratch writes (cross-wave)
    __builtin_amdgcn_s_barrier();
    asm volatile("" ::: "memory");
    if (tid < 256) {
        float m = redM[tid*4+0], s = redS[tid*4+0];
        int   cc = redC[tid*4+0];
        #pragma unroll
        for (int i2 = 1; i2 < 4; i2++) {
            float m2 = redM[tid*4+i2], s2 = redS[tid*4+i2];
            int   c2 = redC[tid*4+i2];
            float nm = fmaxf(m, m2);
            s = s * __expf(m - nm) + s2 * __expf(m2 - nm);
            if (m2 > m) cc = c2;                 // ascending col order; ties keep lower col
            m = nm;
        }
        pp[(size_t)(mb * 256 + tid) * NBLK2 + nb] =
            make_float4(m, s, __int_as_float(nb * 256 + cc), 0.f);
    }
}

// ---------------- fused row tail: policy argmax/lse + exact dot + ref lse + KL ----------------
__global__ __launch_bounds__(256) void row_tail_kernel(
    const float4* __restrict__ part, const float4* __restrict__ part2,
    const float* __restrict__ rx, const float* __restrict__ rw,
    float* __restrict__ klrow)
{
    __shared__ float smM[4], smS[4]; __shared__ int smC[4];
    __shared__ float ss[4];
    __shared__ float sTokLogp; __shared__ int sTok;

    const int row = blockIdx.x, t = threadIdx.x;

    // ---- policy: max / argmax / sumexp over 125 partials ----
    float m = -3.0e38f, s = 0.f; int cc = 0x7fffffff;
    if (t < NBLK2) { float4 p = part[(size_t)row * NBLK2 + t]; m = p.x; s = p.y; cc = __float_as_int(p.z); }
    for (int off = 1; off < 64; off <<= 1) {
        float m2 = __shfl_xor(m, off);
        float s2 = __shfl_xor(s, off);
        int   c2 = __shfl_xor(cc, off);
        float nm = fmaxf(m, m2);
        s = s * __expf(m - nm) + s2 * __expf(m2 - nm);
        if (m2 > m || (m2 == m && c2 < cc)) cc = c2;
        m = nm;
    }
    if ((t & 63) == 0) { smM[t>>6] = m; smS[t>>6] = s; smC[t>>6] = cc; }
    __syncthreads();
    if (t == 0) {
        m = smM[0]; s = smS[0]; cc = smC[0];
        for (int i = 1; i < 4; i++) {
            float m2 = smM[i], s2 = smS[i]; int c2 = smC[i];
            float nm = fmaxf(m, m2);
            s = s * __expf(m - nm) + s2 * __expf(m2 - nm);
            if (m2 > m || (m2 == m && c2 < cc)) cc = c2;
            m = nm;
        }
        sTok = cc;
        sTokLogp = -__logf(s);    // token is argmax -> logit[token] == global max
    }
    __syncthreads();
    const int tok = sTok;

    // ---- exact fp32 dot: rx[row] . rw[tok] ----
    const float4* a = (const float4*)(rx + (size_t)row * H_DIM);
    const float4* b = (const float4*)(rw + (size_t)tok * H_DIM);
    float4 a0 = a[t*2], a1 = a[t*2+1], b0 = b[t*2], b1 = b[t*2+1];
    float d = a0.x*b0.x + a0.y*b0.y + a0.z*b0.z + a0.w*b0.w
            + a1.x*b1.x + a1.y*b1.y + a1.z*b1.z + a1.w*b1.w;
    for (int off = 1; off < 64; off <<= 1) d += __shfl_xor(d, off);
    if ((t & 63) == 0) ss[t >> 6] = d;

    // ---- ref: lse over 125 partials ----
    float mr = -3.0e38f, sr = 0.f;
    if (t < NBLK2) { float4 p = part2[(size_t)row * NBLK2 + t]; mr = p.x; sr = p.y; }
    for (int off = 1; off < 64; off <<= 1) {
        float m2 = __shfl_xor(mr, off), s2 = __shfl_xor(sr, off);
        merge_ms(mr, sr, m2, s2);
    }
    __syncthreads();           // seals ss; frees smM/smS for reuse
    if ((t & 63) == 0) { smM[t>>6] = mr; smS[t>>6] = sr; }
    __syncthreads();
    if (t == 0) {
        mr = smM[0]; sr = smS[0];
        for (int i = 1; i < 4; i++) merge_ms(mr, sr, smM[i], smS[i]);
        float lse = mr + __logf(sr);
        float g = ss[0] + ss[1] + ss[2] + ss[3];
        float dd = (g - lse) - sTokLogp;   // ref_tok_logp - tok_logp
        klrow[row] = __expf(dd) - dd - 1.0f;
    }
}

// ---------------- fallback GEMM (round-1, in-kernel convert + gather) ----------------
__global__ __launch_bounds__(256) void gemm_lse_fallback(
    const float* __restrict__ A, const float* __restrict__ Bw,
    float4* __restrict__ part, const int* __restrict__ token,
    float* __restrict__ gather_out)
{
    __shared__ char smem[TM*TK*2 + TN*TK*2];
    ushort* sA = (ushort*)smem;
    ushort* sB = (ushort*)(smem + TM*TK*2);
    float* redM   = (float*)smem;
    float* redS   = (float*)(smem + 1024);
    int*   redC   = (int*)  (smem + 2048);
    int*   tokloc = (int*)  (smem + 3072);

    const int tid  = threadIdx.x;
    const int lane = tid & 63;
    const int wv   = tid >> 6;
    const int wm   = wv >> 1, wn = wv & 1;
    const int q    = lane >> 4, cl = lane & 15;
    const int m0 = blockIdx.x * TM;
    const int n0 = blockIdx.y * TN;
    const int nb = blockIdx.y;

    const int srow = tid >> 1, sseg = tid & 1;
    const float4* gA = (const float4*)(A  + (size_t)(m0 + srow) * H_DIM) + sseg * 4;
    const float4* gB = (const float4*)(Bw + (size_t)(n0 + srow) * H_DIM) + sseg * 4;
    uint4* wA = (uint4*)sA + srow * 4 + sseg * 2;
    uint4* wB = (uint4*)sB + srow * 4 + sseg * 2;

    f32x4 acc[4][4];
    const f32x4 zero = {0.f, 0.f, 0.f, 0.f};
    #pragma unroll
    for (int i = 0; i < 4; i++)
        #pragma unroll
        for (int j = 0; j < 4; j++) acc[i][j] = zero;

    float4 ra0 = gA[0], ra1 = gA[1], ra2 = gA[2], ra3 = gA[3];
    float4 rb0 = gB[0], rb1 = gB[1], rb2 = gB[2], rb3 = gB[3];

    for (int kt = 0; kt < H_DIM; kt += TK) {
        wA[0] = make_uint4(pack_bf16x2(ra0.x,ra0.y), pack_bf16x2(ra0.z,ra0.w),
                           pack_bf16x2(ra1.x,ra1.y), pack_bf16x2(ra1.z,ra1.w));
        wA[1] = make_uint4(pack_bf16x2(ra2.x,ra2.y), pack_bf16x2(ra2.z,ra2.w),
                           pack_bf16x2(ra3.x,ra3.y), pack_bf16x2(ra3.z,ra3.w));
        wB[0] = make_uint4(pack_bf16x2(rb0.x,rb0.y), pack_bf16x2(rb0.z,rb0.w),
                           pack_bf16x2(rb1.x,rb1.y), pack_bf16x2(rb1.z,rb1.w));
        wB[1] = make_uint4(pack_bf16x2(rb2.x,rb2.y), pack_bf16x2(rb2.z,rb2.w),
                           pack_bf16x2(rb3.x,rb3.y), pack_bf16x2(rb3.z,rb3.w));
        __syncthreads();
        if (kt + TK < H_DIM) {
            int kq = (kt + TK) >> 2;
            ra0 = gA[kq]; ra1 = gA[kq+1]; ra2 = gA[kq+2]; ra3 = gA[kq+3];
            rb0 = gB[kq]; rb1 = gB[kq+1]; rb2 = gB[kq+2]; rb3 = gB[kq+3];
        }
        bf16x8 af[4], bfr[4];
        #pragma unroll
        for (int i = 0; i < 4; i++) {
            af[i]  = *(const bf16x8*)(sA + (wm*64 + i*16 + cl) * TK + q*8);
            bfr[i] = *(const bf16x8*)(sB + (wn*64 + i*16 + cl) * TK + q*8);
        }
        #pragma unroll
        for (int i = 0; i < 4; i++)
            #pragma unroll
            for (int j = 0; j < 4; j++)
                acc[i][j] = __builtin_amdgcn_mfma_f32_16x16x32_bf16(af[i], bfr[j], acc[i][j], 0, 0, 0);
        __syncthreads();
    }

    #pragma unroll
    for (int ti = 0; ti < 4; ti++) {
        #pragma unroll
        for (int r = 0; r < 4; r++) {
            float vals[4];
            #pragma unroll
            for (int j = 0; j < 4; j++) vals[j] = acc[ti][j][r];
            float m = vals[0]; int cj = 0;
            #pragma unroll
            for (int j = 1; j < 4; j++) if (vals[j] > m) { m = vals[j]; cj = j; }
            float s = 0.f;
            #pragma unroll
            for (int j = 0; j < 4; j++) s += __expf(vals[j] - m);
            int cidx = wn*64 + cj*16 + cl;
            #pragma unroll
            for (int off = 1; off < 16; off <<= 1) {
                float m2 = __shfl_xor(m, off);
                float s2 = __shfl_xor(s, off);
                int   c2 = __shfl_xor(cidx, off);
                float nm = fmaxf(m, m2);
                s = s * __expf(m - nm) + s2 * __expf(m2 - nm);
                if (m2 > m || (m2 == m && c2 < cidx)) cidx = c2;
                m = nm;
            }
            int rloc = wm*64 + ti*16 + q*4 + r;
            if (cl == 0) { redM[rloc*2+wn] = m; redS[rloc*2+wn] = s; redC[rloc*2+wn] = cidx; }
        }
    }
    __syncthreads();
    if (tid < TM) {
        float ma = redM[tid*2+0], mb = redM[tid*2+1];
        float sa = redS[tid*2+0], sb = redS[tid*2+1];
        int   ca = redC[tid*2+0], cb = redC[tid*2+1];
        float nm = fmaxf(ma, mb);
        float s  = sa * __expf(ma - nm) + sb * __expf(mb - nm);
        int   cc = (mb > ma || (mb == ma && cb < ca)) ? cb : ca;
        part[(size_t)(m0 + tid) * NBLK_FB + nb] = make_float4(nm, s, __int_as_float(n0 + cc), 0.f);
    }

    if (token != nullptr) {
        if (tid < TM) tokloc[tid] = token[m0 + tid] - n0;
        __syncthreads();
        #pragma unroll
        for (int ti = 0; ti < 4; ti++) {
            #pragma unroll
            for (int r = 0; r < 4; r++) {
                int rloc = wm*64 + ti*16 + q*4 + r;
                int tl = tokloc[rloc];
                if (tl >= 0 && tl < TN && ((tl >> 6) & 1) == wn && (tl & 15) == cl) {
                    int tjm = (tl >> 4) & 3;
                    float v = acc[ti][0][r];
                    if (tjm == 1) v = acc[ti][1][r];
                    if (tjm == 2) v = acc[ti][2][r];
                    if (tjm == 3) v = acc[ti][3][r];
                    gather_out[m0 + rloc] = v;
                }
            }
        }
    }
}

// ---------------- fallback reductions ----------------

__global__ __launch_bounds__(256) void reduce_policy_kernel(
    const float4* __restrict__ part, int* __restrict__ token, float* __restrict__ tok_logp,
    int nblk)
{
    int row = blockIdx.x, t = threadIdx.x;
    float m = -3.0e38f, s = 0.f; int cc = 0x7fffffff;
    if (t < nblk) { float4 p = part[(size_t)row * nblk + t]; m = p.x; s = p.y; cc = __float_as_int(p.z); }
    for (int off = 1; off < 64; off <<= 1) {
        float m2 = __shfl_xor(m, off);
        float s2 = __shfl_xor(s, off);
        int   c2 = __shfl_xor(cc, off);
        float nm = fmaxf(m, m2);
        s = s * __expf(m - nm) + s2 * __expf(m2 - nm);
        if (m2 > m || (m2 == m && c2 < cc)) cc = c2;
        m = nm;
    }
    __shared__ float smM[4], smS[4]; __shared__ int smC[4];
    if ((t & 63) == 0) { smM[t>>6] = m; smS[t>>6] = s; smC[t>>6] = cc; }
    __syncthreads();
    if (t == 0) {
        m = smM[0]; s = smS[0]; cc = smC[0];
        for (int i = 1; i < 4; i++) {
            float m2 = smM[i], s2 = smS[i]; int c2 = smC[i];
            float nm = fmaxf(m, m2);
            s = s * __expf(m - nm) + s2 * __expf(m2 - nm);
            if (m2 > m || (m2 == m && c2 < cc)) cc = c2;
            m = nm;
        }
        token[row] = cc;
        tok_logp[row] = -__logf(s);
    }
}

__global__ __launch_bounds__(256) void dot_gather_kernel(
    const float* __restrict__ rx, const float* __restrict__ rw,
    const int* __restrict__ token, float* __restrict__ out)
{
    int row = blockIdx.x, t = threadIdx.x;
    const float4* a = (const float4*)(rx + (size_t)row * H_DIM);
    const float4* b = (const float4*)(rw + (size_t)token[row] * H_DIM);
    float4 a0 = a[t*2], a1 = a[t*2+1], b0 = b[t*2], b1 = b[t*2+1];
    float s = a0.x*b0.x + a0.y*b0.y + a0.z*b0.z + a0.w*b0.w
            + a1.x*b1.x + a1.y*b1.y + a1.z*b1.z + a1.w*b1.w;
    for (int off = 1; off < 64; off <<= 1) s += __shfl_xor(s, off);
    __shared__ float ss[4];
    if ((t & 63) == 0) ss[t >> 6] = s;
    __syncthreads();
    if (t == 0) out[row] = ss[0] + ss[1] + ss[2] + ss[3];
}

__global__ __launch_bounds__(256) void reduce_ref_kernel(
    const float4* __restrict__ part, const float* __restrict__ tok_logp,
    const float* __restrict__ gathered, float* __restrict__ klrow, int nblk)
{
    int row = blockIdx.x, t = threadIdx.x;
    float m = -3.0e38f, s = 0.f;
    if (t < nblk) { float4 p = part[(size_t)row * nblk + t]; m = p.x; s = p.y; }
    for (int off = 1; off < 64; off <<= 1) {
        float m2 = __shfl_xor(m, off), s2 = __shfl_xor(s, off);
        merge_ms(m, s, m2, s2);
    }
    __shared__ float smM[4], smS[4];
    if ((t & 63) == 0) { smM[t>>6] = m; smS[t>>6] = s; }
    __syncthreads();
    if (t == 0) {
        m = smM[0]; s = smS[0];
        for (int i = 1; i < 4; i++) merge_ms(m, s, smM[i], smS[i]);
        float lse = m + __logf(s);
        float d = (gathered[row] - lse) - tok_logp[row];
        klrow[row] = __expf(d) - d - 1.0f;
    }
}

__global__ __launch_bounds__(256) void final_kernel(
    const int* __restrict__ amask, const float* __restrict__ rewards,
    const float* __restrict__ klrow, float* __restrict__ out)
{
    int t = threadIdx.x;
    int b = t >> 5;
    int g = b >> 2;
    float r0 = rewards[g*4+0], r1 = rewards[g*4+1], r2 = rewards[g*4+2], r3 = rewards[g*4+3];
    float mean = 0.25f * (r0 + r1 + r2 + r3);
    float var = ((r0-mean)*(r0-mean) + (r1-mean)*(r1-mean) +
                 (r2-mean)*(r2-mean) + (r3-mean)*(r3-mean)) * (1.0f/3.0f);  // ddof=1
    float adv = (rewards[b] - mean) / (sqrtf(var) + EPSR);

    float ln = 0.f, ms = 0.f, kb = 0.f, mb = 0.f;
    for (int i = 0; i < 8; i++) {
        int row = t*8 + i;
        float mk = (float)amask[row];
        float kl = klrow[row];
        ln += (adv - BETA * kl) * mk;
        ms += mk;
        kb += kl * mk;
        mb += mk;
    }
    __shared__ float sLN[256], sMS[256], sKB[256], sMB[256], sKLb[8];
    sLN[t] = ln; sMS[t] = ms; sKB[t] = kb; sMB[t] = mb;
    __syncthreads();
    if (t < 8) {
        float skb = 0.f, smb = 0.f;
        for (int i = 0; i < 32; i++) { skb += sKB[t*32+i]; smb += sMB[t*32+i]; }
        sKLb[t] = skb / smb;
    }
    __syncthreads();
    if (t == 0) {
        float lnt = 0.f, mst = 0.f;
        for (int i = 0; i < 256; i++) { lnt += sLN[i]; mst += sMS[i]; }
        float mkl = 0.f;
        for (int i = 0; i < 8; i++) mkl += sKLb[i];
        out[0] = -lnt / mst;
        out[1] = mkl * 0.125f;
    }
}

// ---------------- launch ----------------

extern "C" void kernel_launch(void* const* d_in, const int* in_sizes, int n_in,
                              void* d_out, int out_size, void* d_ws, size_t ws_size,
                              hipStream_t stream)
{
    const float* x       = (const float*)d_in[0];
    const float* w       = (const float*)d_in[1];
    const int*   amask   = (const int*)  d_in[2];
    const float* rewards = (const float*)d_in[3];
    const float* rx      = (const float*)d_in[4];
    const float* rw      = (const float*)d_in[5];
    float* out = (float*)d_out;
    char* ws = (char*)d_ws;

    const size_t W_P  = (size_t)V_DIM * H_DIM * 2;   // 131,072,000 bf16 bytes (ONE buffer)
    const size_t A_P  = (size_t)BT * H_DIM * 2;      //   8,388,608
    const size_t PART = (size_t)BT * NBLK2 * 16;     //   4,096,000
    const size_t NEED = W_P + 2*A_P + 2*PART + 32768;   // 156 MB

    if (ws_size >= NEED) {
        // ---- fast path (R7 launch structure): shared weight slab buffer packed twice
        // (w, then rw after gemm1 -- stream order serializes, no overwrite race).
        ushort* Wp   = (ushort*)(ws);                 // shared slab buffer (w, then rw)
        ushort* Ap   = (ushort*)(ws + W_P);
        ushort* Rp   = (ushort*)(ws + W_P + A_P);
        float4* part  = (float4*)(ws + W_P + 2*A_P);
        float4* part2 = (float4*)(ws + W_P + 2*A_P + PART);
        char*   tail  =          ws + W_P + 2*A_P + 2*PART;
        float* klrow    = (float*)(tail);

        pack_act_kernel<<<dim3(256),  512, 0, stream>>>(x, rx, (uint4*)Ap, (uint4*)Rp);
        pack_w_kernel  <<<dim3(2000), 512, 0, stream>>>(w, (uint4*)Wp);

        gemm_lse_v10<<<dim3(1000), 512, 0, stream>>>(Ap, Wp, part);    // policy

        pack_w_kernel  <<<dim3(2000), 512, 0, stream>>>(rw, (uint4*)Wp);

        gemm_lse_v10<<<dim3(1000), 512, 0, stream>>>(Rp, Wp, part2);   // reference

        row_tail_kernel<<<BT, 256, 0, stream>>>(part, part2, rx, rw, klrow);
        final_kernel<<<1, 256, 0, stream>>>(amask, rewards, klrow, out);
    } else {
        // ---- fallback: round-1 path (ws too small for packed weights) ----
        const size_t PART_FB = (size_t)BT * NBLK_FB * 16;
        float4* part     = (float4*)ws;
        int*    token    = (int*)  (ws + PART_FB);
        float*  tok_logp = (float*)(ws + PART_FB + 8192);
        float*  gathered = (float*)(ws + PART_FB + 16384);
        float*  klrow    = (float*)(ws + PART_FB + 24576);

        dim3 g(BT / TM, NBLK_FB), blk(256);
        gemm_lse_fallback<<<g, blk, 0, stream>>>(x, w, part, nullptr, nullptr);
        reduce_policy_kernel<<<BT, 256, 0, stream>>>(part, token, tok_logp, NBLK_FB);
        gemm_lse_fallback<<<g, blk, 0, stream>>>(rx, rw, part, token, gathered);
        reduce_ref_kernel<<<BT, 256, 0, stream>>>(part, tok_logp, gathered, klrow, NBLK_FB);
        final_kernel<<<1, 256, 0, stream>>>(amask, rewards, klrow, out);
    }
}

// Round 11
// 1080.193 us; speedup vs baseline: 1.0454x; 1.0454x over previous
//
#include <hip/hip_runtime.h>
#include <hip/hip_bf16.h>
#include <math.h>

// Problem constants (fixed by the reference: H=2048, V=32000, B=8, T=256, G=4).
#define H_DIM 2048
#define V_DIM 32000
#define BT    2048            // B*T rows
#define BETA  0.1f
#define EPSR  1e-4f

// ---- fast-path GEMM geometry: 256x256 tile, BK=64, 8 waves (2M x 4N) ----
#define NT    32              // K tiles of 64 (H/64)
#define NBLK2 125             // V / 256
// ---- fallback geometry (round-1 kernel, unchanged) ----
#define TM 128
#define TN 128
#define TK 32
#define NBLK_FB 250

typedef __attribute__((ext_vector_type(8))) short bf16x8;   // 8 bf16 = 4 VGPRs
typedef __attribute__((ext_vector_type(4))) float f32x4;

// ---------------- helpers ----------------

// Pack two fp32 -> bf16x2 (round-half-up via +0x8000, take high 16 bits each).
__device__ __forceinline__ unsigned pack_bf16x2(float a, float b) {
    unsigned ua = __float_as_uint(a) + 0x8000u;
    unsigned ub = __float_as_uint(b) + 0x8000u;
    return __builtin_amdgcn_perm(ub, ua, 0x07060302u);
}

__device__ __forceinline__ void merge_ms(float& m, float& s, float m2, float s2) {
    float nm = fmaxf(m, m2);
    s = s * __expf(m - nm) + s2 * __expf(m2 - nm);
    m = nm;
}

// Async global->LDS, 16 B per lane. LDS dest = wave-uniform base + lane*16.
__device__ __forceinline__ void gl_lds16(const void* g, void* l) {
    __builtin_amdgcn_global_load_lds(
        (const __attribute__((address_space(1))) void*)g,
        (__attribute__((address_space(3))) void*)l, 16, 0, 0);
}

// ---------------- linear pack: fp32 [R,2048] -> bf16 slabs per (256-row, 64-K) tile --------
// Slab (rt,kt) is 32 KB: chunk (kk*256+row) holds src[rt*256+row][kt*64+kk*8..+8] as 8 bf16.
// 512 threads/block; reads fully linear (16 rows x 8KB contiguous); writes 256B segments.
#define PROWS 16

__device__ __forceinline__ void pack_rows(
    const float* __restrict__ src, uint4* __restrict__ dst, int rb, int t,
    ushort (*tile)[2056])
{
    const int r0    = rb * PROWS;          // first global row of this block
    const int rt    = r0 >> 8;             // slab row-tile (256-row units)
    const int rbase = r0 & 255;            // row offset within the slab

    const float4* s4 = (const float4*)(src + (size_t)r0 * H_DIM);
    #pragma unroll
    for (int i = 0; i < PROWS; i++) {
        float4 v = s4[i * 512 + t];
        uint2 b;
        b.x = pack_bf16x2(v.x, v.y);
        b.y = pack_bf16x2(v.z, v.w);
        *(uint2*)&tile[i][t * 4] = b;                  // 8B store
    }
    __syncthreads();

    #pragma unroll
    for (int i = 0; i < 8; i++) {
        int c   = i * 512 + t;                         // 0..4095
        int kt  = c >> 7, kk = (c >> 4) & 7, row = c & 15;
        uint4 v = *(const uint4*)&tile[row][kt * 64 + kk * 8];
        dst[(((size_t)rt * NT + kt) << 11) + kk * 256 + rbase + row] = v;
    }
}

// Activations: x (blocks 0..127) and rx (blocks 128..255).
__global__ __launch_bounds__(512) void pack_act_kernel(
    const float* __restrict__ x, const float* __restrict__ rx,
    uint4* __restrict__ Ap, uint4* __restrict__ Rp)
{
    __shared__ __align__(16) ushort tile[PROWS][2056];   // 65,792 B -> 2 blocks/CU
    const int bx = blockIdx.x;
    if (bx < 128) pack_rows(x,  Ap, bx,       threadIdx.x, tile);
    else          pack_rows(rx, Rp, bx - 128, threadIdx.x, tile);
}

// One weight matrix -> the SHARED weight slab buffer (called twice, stream-serialized
// around gemm1 so w's slabs are consumed before rw overwrites them).
__global__ __launch_bounds__(512) void pack_w_kernel(
    const float* __restrict__ src, uint4* __restrict__ dst)
{
    __shared__ __align__(16) ushort tile[PROWS][2056];
    pack_rows(src, dst, blockIdx.x, threadIdx.x, tile);
}

// ---------------- 256^2 8-phase GEMM v7 (best measured: R7, 1078 us total) -------------
// One dispatch per model, grid 1000. Work index l = (bid%8)*125 + bid/8; mb = l&7 fastest:
// 8 co-resident same-XCD blocks share one B-panel (L2-served; proven R3).
// A-fragments for phase p+1 are ds_read-issued during phase p into a second register set.
// Barrier positions and the vmcnt ledger are the R4-verified structure (one barrier per
// phase; vmcnt(6)+publication barrier at p4/p8 only). R10 confirmed (m196-style) that
// COARSER phase granularity regresses -- this fine interleave is the local optimum.

#define MF(a,b,c) __builtin_amdgcn_mfma_f32_16x16x32_bf16(a, b, c, 0, 0, 0)

#define LDA(dst, BUF, F, KS) \
    dst = *(const bf16x8*)(smem + (BUF)*65536 + (KS)*16384 + (F)*256 + aoff)
#define LDB(dst, BUF, CF, KS) \
    dst = *(const bf16x8*)(smem + (BUF)*65536 + (KS)*16384 + (CF)*256 + boff)

#define STAGE(SG, SHT, SBUF) do { \
    const char* s_ = ((SHT) < 2 ? Bbase : Abase) + ((size_t)(SG) << 15); \
    char* l_ = smem + (SBUF)*65536 + ((SHT) < 2 ? 32768 : 0); \
    gl_lds16(s_ + soff[SHT][0], l_ + soff[SHT][0]); \
    gl_lds16(s_ + soff[SHT][1], l_ + soff[SHT][1]); \
} while (0)

#define MFMA_PH(F0, A0, A1, A2, A3) do { \
    acc[F0][0]   = MF(A0, bfr[0][0], acc[F0][0]); \
    acc[F0][1]   = MF(A0, bfr[1][0], acc[F0][1]); \
    acc[F0][2]   = MF(A0, bfr[2][0], acc[F0][2]); \
    acc[F0][3]   = MF(A0, bfr[3][0], acc[F0][3]); \
    acc[F0+1][0] = MF(A2, bfr[0][0], acc[F0+1][0]); \
    acc[F0+1][1] = MF(A2, bfr[1][0], acc[F0+1][1]); \
    acc[F0+1][2] = MF(A2, bfr[2][0], acc[F0+1][2]); \
    acc[F0+1][3] = MF(A2, bfr[3][0], acc[F0+1][3]); \
    acc[F0][0]   = MF(A1, bfr[0][1], acc[F0][0]); \
    acc[F0][1]   = MF(A1, bfr[1][1], acc[F0][1]); \
    acc[F0][2]   = MF(A1, bfr[2][1], acc[F0][2]); \
    acc[F0][3]   = MF(A1, bfr[3][1], acc[F0][3]); \
    acc[F0+1][0] = MF(A3, bfr[0][1], acc[F0+1][0]); \
    acc[F0+1][1] = MF(A3, bfr[1][1], acc[F0+1][1]); \
    acc[F0+1][2] = MF(A3, bfr[2][1], acc[F0+1][2]); \
    acc[F0+1][3] = MF(A3, bfr[3][1], acc[F0+1][3]); \
} while (0)

// One phase. FC: acc row / current frags AFC (ds_read-issued LAST phase). AFN: register
// set receiving NEXT phase's frags from (BUFN, FN) -- issued here, consumed next phase.
// VM: vmcnt(6)+publication barrier FIRST (p4/p8) so cross-buffer prefetch reads sealed
// data. POSTB: B-frag reloads post-MFMA from PBUF for the next 4 phases.
#define PHASEP(FC, AFC, AFN, BUFN, FN, SG, SHT, SBUF, VM, POSTB, PBUF) do { \
    if (VM) { \
        asm volatile("s_waitcnt vmcnt(6)" ::: "memory"); \
        __builtin_amdgcn_s_barrier(); \
        asm volatile("" ::: "memory"); \
    } \
    LDA(AFN[0], BUFN, FN,   0); LDA(AFN[1], BUFN, FN,   1); \
    LDA(AFN[2], BUFN, FN+1, 0); LDA(AFN[3], BUFN, FN+1, 1); \
    STAGE(SG, SHT, SBUF); \
    __builtin_amdgcn_s_setprio(1); \
    MFMA_PH(FC, AFC[0], AFC[1], AFC[2], AFC[3]); \
    __builtin_amdgcn_s_setprio(0); \
    if (POSTB) { \
        LDB(bfr[0][0], PBUF, 0, 0); LDB(bfr[0][1], PBUF, 0, 1); \
        LDB(bfr[1][0], PBUF, 1, 0); LDB(bfr[1][1], PBUF, 1, 1); \
        LDB(bfr[2][0], PBUF, 2, 0); LDB(bfr[2][1], PBUF, 2, 1); \
        LDB(bfr[3][0], PBUF, 3, 0); LDB(bfr[3][1], PBUF, 3, 1); \
    } \
    asm volatile("" ::: "memory"); \
    __builtin_amdgcn_s_barrier(); \
    asm volatile("" ::: "memory"); \
} while (0)

__global__ __launch_bounds__(512, 2) void gemm_lse_v7(
    const ushort* __restrict__ Apk, const ushort* __restrict__ Bpk,
    float4* __restrict__ pp)
{
    __shared__ __align__(16) char smem_raw[131072 + 12288];  // tiles | epilogue scratch
    char* smem = smem_raw;
    float* redM = (float*)(smem_raw + 131072);               // 256 rows x 4 wn-segments
    float* redS = (float*)(smem_raw + 131072 + 4096);
    int*   redC = (int*)  (smem_raw + 131072 + 8192);

    const int tid  = threadIdx.x;
    const int lane = tid & 63;
    const int wv   = tid >> 6;                          // 0..7
    const int wm   = wv >> 2, wn = wv & 3;              // 2 x 4 wave grid: 128x64 per wave
    const int q    = lane >> 4, cl = lane & 15;

    // XCD-chunked work mapping: bid%8 ~ XCD (dispatch round-robin heuristic; speed-only).
    const int bid = blockIdx.x;                         // 0..999
    const int l   = (bid & 7) * 125 + (bid >> 3);       // bijective
    const int mb  = l & 7;                              // varies fastest: 8 blocks share panel
    const int nb  = l >> 3;                             // 0..124 = B-panel

    const char* Abase = (const char*)Apk + ((size_t)(mb * NT) << 15);
    const char* Bbase = (const char*)Bpk + ((size_t)(nb * NT) << 15);

    // Fragment-read base offsets (within a 64 KB tile-buffer).
    const int aoff = q * 4096 + (wm * 128 + cl) * 16;
    const int boff = 32768 + q * 4096 + (wn * 64 + cl) * 16;

    // Staging offsets: chunk c = wv*2 + li covers (kk, row-group), 64 rows/lane.
    int soff[4][2];
    #pragma unroll
    for (int li = 0; li < 2; li++) {
        int c = wv * 2 + li;
        int kko = (((c >> 3) << 2) + ((c >> 1) & 3)) * 4096;
        int rg = c & 1;
        soff[0][li] = kko + (rg * 64 + lane) * 16;            // B rows 0..128
        soff[1][li] = kko + (128 + rg * 64 + lane) * 16;      // B rows 128..256
        soff[2][li] = kko + (rg * 128 + lane) * 16;           // A rows {0-64, 128-192}
        soff[3][li] = kko + (rg * 128 + 64 + lane) * 16;      // A rows {64-128, 192-256}
    }

    f32x4 acc[8][4];
    const f32x4 zero = {0.f, 0.f, 0.f, 0.f};
    #pragma unroll
    for (int i = 0; i < 8; i++)
        #pragma unroll
        for (int j = 0; j < 4; j++) acc[i][j] = zero;

    bf16x8 bfr[4][2];
    bf16x8 afX[4], afY[4];      // double-buffered A-frag register sets

    // Prologue: tile0 (4 HTs) -> buf0, tile1 (ht0..2) -> buf1; 14 loads, keep 6 in flight.
    STAGE(0, 0, 0); STAGE(0, 1, 0); STAGE(0, 2, 0); STAGE(0, 3, 0);
    STAGE(1, 0, 1); STAGE(1, 1, 1); STAGE(1, 2, 1);
    asm volatile("s_waitcnt vmcnt(6)" ::: "memory");
    __builtin_amdgcn_s_barrier();
    asm volatile("" ::: "memory");
    // Initial B frags (tile 0, buf0) + p1's A frags (buf0, F0-1) into set X.
    LDB(bfr[0][0], 0, 0, 0); LDB(bfr[0][1], 0, 0, 1);
    LDB(bfr[1][0], 0, 1, 0); LDB(bfr[1][1], 0, 1, 1);
    LDB(bfr[2][0], 0, 2, 0); LDB(bfr[2][1], 0, 2, 1);
    LDB(bfr[3][0], 0, 3, 0); LDB(bfr[3][1], 0, 3, 1);
    LDA(afX[0], 0, 0, 0); LDA(afX[1], 0, 0, 1);
    LDA(afX[2], 0, 1, 0); LDA(afX[3], 0, 1, 1);

    #pragma unroll 1
    for (int ii = 0; ii < 16; ii++) {
        int t1 = 2 * ii + 1;
        int t2 = 2 * ii + 2; if (t2 > NT - 1) t2 = NT - 1;  // tail: dummy (valid) stages,
        int t3 = 2 * ii + 3; if (t3 > NT - 1) t3 = NT - 1;  // keeps the vmcnt ledger exact
        //      FC  cur  nxt  BUFN FN  SG  HT  SB  VM PB PBUF
        PHASEP( 0, afX, afY, 0,   2, t1, 3,  1,  0, 0, 0);   // p1
        PHASEP( 2, afY, afX, 0,   4, t2, 0,  0,  0, 0, 0);   // p2
        PHASEP( 4, afX, afY, 0,   6, t2, 1,  0,  0, 0, 0);   // p3
        PHASEP( 6, afY, afX, 1,   0, t2, 2,  0,  1, 1, 1);   // p4: vm+pub; postB(buf1)
        PHASEP( 0, afX, afY, 1,   2, t2, 3,  0,  0, 0, 0);   // p5
        PHASEP( 2, afY, afX, 1,   4, t3, 0,  1,  0, 0, 0);   // p6
        PHASEP( 4, afX, afY, 1,   6, t3, 1,  1,  0, 0, 0);   // p7
        PHASEP( 6, afY, afX, 0,   0, t3, 2,  1,  1, 1, 0);   // p8: vm+pub; postB(buf0)
    }

    // ---- epilogue: per-row {max, argmax col, sumexp} over this block's 256 cols ----
    // C layout (m89): col = cf*16 + cl (+ wn*64), row = f*16 + q*4 + reg (+ wm*128).
    // Remaining in-flight dummy loads target the tile buffers (<128KB); scratch is above.
    #pragma unroll
    for (int f = 0; f < 8; f++) {
        #pragma unroll
        for (int r = 0; r < 4; r++) {
            float v0 = acc[f][0][r], v1 = acc[f][1][r], v2 = acc[f][2][r], v3 = acc[f][3][r];
            float m = v0; int cj = 0;
            if (v1 > m) { m = v1; cj = 1; }
            if (v2 > m) { m = v2; cj = 2; }
            if (v3 > m) { m = v3; cj = 3; }
            float s = __expf(v0 - m) + __expf(v1 - m) + __expf(v2 - m) + __expf(v3 - m);
            int cidx = wn * 64 + cj * 16 + cl;
            #pragma unroll
            for (int off = 1; off < 16; off <<= 1) {
                float m2 = __shfl_xor(m, off);
                float s2 = __shfl_xor(s, off);
                int   c2 = __shfl_xor(cidx, off);
                float nm = fmaxf(m, m2);
                s = s * __expf(m - nm) + s2 * __expf(m2 - nm);
                if (m2 > m || (m2 == m && c2 < cidx)) cidx = c2;   // first-occurrence ties
                m = nm;
            }
            int rloc = wm * 128 + f * 16 + q * 4 + r;
            if (cl == 0) { redM[rloc*4+wn] = m; redS[rloc*4+wn] = s; redC[rloc*4+wn] = cidx; }
        }
    }
    asm volatile("s_waitcnt lgkmcnt(0)" ::: "memory");   // seal scratch writes (cross-wave)
    __builtin_amdgcn_s_barrier();
    asm volatile("" ::: "memory");
    if (tid < 256) {
        float m = redM[tid*4+0], s = redS[tid*4+0];
        int   cc = redC[tid*4+0];
        #pragma unroll
        for (int i2 = 1; i2 < 4; i2++) {
            float m2 = redM[tid*4+i2], s2 = redS[tid*4+i2];
            int   c2 = redC[tid*4+i2];
            float nm = fmaxf(m, m2);
            s = s * __expf(m - nm) + s2 * __expf(m2 - nm);
            if (m2 > m) cc = c2;                 // ascending col order; ties keep lower col
            m = nm;
        }
        pp[(size_t)(mb * 256 + tid) * NBLK2 + nb] =
            make_float4(m, s, __int_as_float(nb * 256 + cc), 0.f);
    }
}

// ---------------- fused row tail: policy argmax/lse + exact dot + ref lse + KL ----------------
__global__ __launch_bounds__(256) void row_tail_kernel(
    const float4* __restrict__ part, const float4* __restrict__ part2,
    const float* __restrict__ rx, const float* __restrict__ rw,
    float* __restrict__ klrow)
{
    __shared__ float smM[4], smS[4]; __shared__ int smC[4];
    __shared__ float ss[4];
    __shared__ float sTokLogp; __shared__ int sTok;

    const int row = blockIdx.x, t = threadIdx.x;

    // ---- policy: max / argmax / sumexp over 125 partials ----
    float m = -3.0e38f, s = 0.f; int cc = 0x7fffffff;
    if (t < NBLK2) { float4 p = part[(size_t)row * NBLK2 + t]; m = p.x; s = p.y; cc = __float_as_int(p.z); }
    for (int off = 1; off < 64; off <<= 1) {
        float m2 = __shfl_xor(m, off);
        float s2 = __shfl_xor(s, off);
        int   c2 = __shfl_xor(cc, off);
        float nm = fmaxf(m, m2);
        s = s * __expf(m - nm) + s2 * __expf(m2 - nm);
        if (m2 > m || (m2 == m && c2 < cc)) cc = c2;
        m = nm;
    }
    if ((t & 63) == 0) { smM[t>>6] = m; smS[t>>6] = s; smC[t>>6] = cc; }
    __syncthreads();
    if (t == 0) {
        m = smM[0]; s = smS[0]; cc = smC[0];
        for (int i = 1; i < 4; i++) {
            float m2 = smM[i], s2 = smS[i]; int c2 = smC[i];
            float nm = fmaxf(m, m2);
            s = s * __expf(m - nm) + s2 * __expf(m2 - nm);
            if (m2 > m || (m2 == m && c2 < cc)) cc = c2;
            m = nm;
        }
        sTok = cc;
        sTokLogp = -__logf(s);    // token is argmax -> logit[token] == global max
    }
    __syncthreads();
    const int tok = sTok;

    // ---- exact fp32 dot: rx[row] . rw[tok] ----
    const float4* a = (const float4*)(rx + (size_t)row * H_DIM);
    const float4* b = (const float4*)(rw + (size_t)tok * H_DIM);
    float4 a0 = a[t*2], a1 = a[t*2+1], b0 = b[t*2], b1 = b[t*2+1];
    float d = a0.x*b0.x + a0.y*b0.y + a0.z*b0.z + a0.w*b0.w
            + a1.x*b1.x + a1.y*b1.y + a1.z*b1.z + a1.w*b1.w;
    for (int off = 1; off < 64; off <<= 1) d += __shfl_xor(d, off);
    if ((t & 63) == 0) ss[t >> 6] = d;

    // ---- ref: lse over 125 partials ----
    float mr = -3.0e38f, sr = 0.f;
    if (t < NBLK2) { float4 p = part2[(size_t)row * NBLK2 + t]; mr = p.x; sr = p.y; }
    for (int off = 1; off < 64; off <<= 1) {
        float m2 = __shfl_xor(mr, off), s2 = __shfl_xor(sr, off);
        merge_ms(mr, sr, m2, s2);
    }
    __syncthreads();           // seals ss; frees smM/smS for reuse
    if ((t & 63) == 0) { smM[t>>6] = mr; smS[t>>6] = sr; }
    __syncthreads();
    if (t == 0) {
        mr = smM[0]; sr = smS[0];
        for (int i = 1; i < 4; i++) merge_ms(mr, sr, smM[i], smS[i]);
        float lse = mr + __logf(sr);
        float g = ss[0] + ss[1] + ss[2] + ss[3];
        float dd = (g - lse) - sTokLogp;   // ref_tok_logp - tok_logp
        klrow[row] = __expf(dd) - dd - 1.0f;
    }
}

// ---------------- fallback GEMM (round-1, in-kernel convert + gather) ----------------
__global__ __launch_bounds__(256) void gemm_lse_fallback(
    const float* __restrict__ A, const float* __restrict__ Bw,
    float4* __restrict__ part, const int* __restrict__ token,
    float* __restrict__ gather_out)
{
    __shared__ char smem[TM*TK*2 + TN*TK*2];
    ushort* sA = (ushort*)smem;
    ushort* sB = (ushort*)(smem + TM*TK*2);
    float* redM   = (float*)smem;
    float* redS   = (float*)(smem + 1024);
    int*   redC   = (int*)  (smem + 2048);
    int*   tokloc = (int*)  (smem + 3072);

    const int tid  = threadIdx.x;
    const int lane = tid & 63;
    const int wv   = tid >> 6;
    const int wm   = wv >> 1, wn = wv & 1;
    const int q    = lane >> 4, cl = lane & 15;
    const int m0 = blockIdx.x * TM;
    const int n0 = blockIdx.y * TN;
    const int nb = blockIdx.y;

    const int srow = tid >> 1, sseg = tid & 1;
    const float4* gA = (const float4*)(A  + (size_t)(m0 + srow) * H_DIM) + sseg * 4;
    const float4* gB = (const float4*)(Bw + (size_t)(n0 + srow) * H_DIM) + sseg * 4;
    uint4* wA = (uint4*)sA + srow * 4 + sseg * 2;
    uint4* wB = (uint4*)sB + srow * 4 + sseg * 2;

    f32x4 acc[4][4];
    const f32x4 zero = {0.f, 0.f, 0.f, 0.f};
    #pragma unroll
    for (int i = 0; i < 4; i++)
        #pragma unroll
        for (int j = 0; j < 4; j++) acc[i][j] = zero;

    float4 ra0 = gA[0], ra1 = gA[1], ra2 = gA[2], ra3 = gA[3];
    float4 rb0 = gB[0], rb1 = gB[1], rb2 = gB[2], rb3 = gB[3];

    for (int kt = 0; kt < H_DIM; kt += TK) {
        wA[0] = make_uint4(pack_bf16x2(ra0.x,ra0.y), pack_bf16x2(ra0.z,ra0.w),
                           pack_bf16x2(ra1.x,ra1.y), pack_bf16x2(ra1.z,ra1.w));
        wA[1] = make_uint4(pack_bf16x2(ra2.x,ra2.y), pack_bf16x2(ra2.z,ra2.w),
                           pack_bf16x2(ra3.x,ra3.y), pack_bf16x2(ra3.z,ra3.w));
        wB[0] = make_uint4(pack_bf16x2(rb0.x,rb0.y), pack_bf16x2(rb0.z,rb0.w),
                           pack_bf16x2(rb1.x,rb1.y), pack_bf16x2(rb1.z,rb1.w));
        wB[1] = make_uint4(pack_bf16x2(rb2.x,rb2.y), pack_bf16x2(rb2.z,rb2.w),
                           pack_bf16x2(rb3.x,rb3.y), pack_bf16x2(rb3.z,rb3.w));
        __syncthreads();
        if (kt + TK < H_DIM) {
            int kq = (kt + TK) >> 2;
            ra0 = gA[kq]; ra1 = gA[kq+1]; ra2 = gA[kq+2]; ra3 = gA[kq+3];
            rb0 = gB[kq]; rb1 = gB[kq+1]; rb2 = gB[kq+2]; rb3 = gB[kq+3];
        }
        bf16x8 af[4], bfr[4];
        #pragma unroll
        for (int i = 0; i < 4; i++) {
            af[i]  = *(const bf16x8*)(sA + (wm*64 + i*16 + cl) * TK + q*8);
            bfr[i] = *(const bf16x8*)(sB + (wn*64 + i*16 + cl) * TK + q*8);
        }
        #pragma unroll
        for (int i = 0; i < 4; i++)
            #pragma unroll
            for (int j = 0; j < 4; j++)
                acc[i][j] = __builtin_amdgcn_mfma_f32_16x16x32_bf16(af[i], bfr[j], acc[i][j], 0, 0, 0);
        __syncthreads();
    }

    #pragma unroll
    for (int ti = 0; ti < 4; ti++) {
        #pragma unroll
        for (int r = 0; r < 4; r++) {
            float vals[4];
            #pragma unroll
            for (int j = 0; j < 4; j++) vals[j] = acc[ti][j][r];
            float m = vals[0]; int cj = 0;
            #pragma unroll
            for (int j = 1; j < 4; j++) if (vals[j] > m) { m = vals[j]; cj = j; }
            float s = 0.f;
            #pragma unroll
            for (int j = 0; j < 4; j++) s += __expf(vals[j] - m);
            int cidx = wn*64 + cj*16 + cl;
            #pragma unroll
            for (int off = 1; off < 16; off <<= 1) {
                float m2 = __shfl_xor(m, off);
                float s2 = __shfl_xor(s, off);
                int   c2 = __shfl_xor(cidx, off);
                float nm = fmaxf(m, m2);
                s = s * __expf(m - nm) + s2 * __expf(m2 - nm);
                if (m2 > m || (m2 == m && c2 < cidx)) cidx = c2;
                m = nm;
            }
            int rloc = wm*64 + ti*16 + q*4 + r;
            if (cl == 0) { redM[rloc*2+wn] = m; redS[rloc*2+wn] = s; redC[rloc*2+wn] = cidx; }
        }
    }
    __syncthreads();
    if (tid < TM) {
        float ma = redM[tid*2+0], mb = redM[tid*2+1];
        float sa = redS[tid*2+0], sb = redS[tid*2+1];
        int   ca = redC[tid*2+0], cb = redC[tid*2+1];
        float nm = fmaxf(ma, mb);
        float s  = sa * __expf(ma - nm) + sb * __expf(mb - nm);
        int   cc = (mb > ma || (mb == ma && cb < ca)) ? cb : ca;
        part[(size_t)(m0 + tid) * NBLK_FB + nb] = make_float4(nm, s, __int_as_float(n0 + cc), 0.f);
    }

    if (token != nullptr) {
        if (tid < TM) tokloc[tid] = token[m0 + tid] - n0;
        __syncthreads();
        #pragma unroll
        for (int ti = 0; ti < 4; ti++) {
            #pragma unroll
            for (int r = 0; r < 4; r++) {
                int rloc = wm*64 + ti*16 + q*4 + r;
                int tl = tokloc[rloc];
                if (tl >= 0 && tl < TN && ((tl >> 6) & 1) == wn && (tl & 15) == cl) {
                    int tjm = (tl >> 4) & 3;
                    float v = acc[ti][0][r];
                    if (tjm == 1) v = acc[ti][1][r];
                    if (tjm == 2) v = acc[ti][2][r];
                    if (tjm == 3) v = acc[ti][3][r];
                    gather_out[m0 + rloc] = v;
                }
            }
        }
    }
}

// ---------------- fallback reductions ----------------

__global__ __launch_bounds__(256) void reduce_policy_kernel(
    const float4* __restrict__ part, int* __restrict__ token, float* __restrict__ tok_logp,
    int nblk)
{
    int row = blockIdx.x, t = threadIdx.x;
    float m = -3.0e38f, s = 0.f; int cc = 0x7fffffff;
    if (t < nblk) { float4 p = part[(size_t)row * nblk + t]; m = p.x; s = p.y; cc = __float_as_int(p.z); }
    for (int off = 1; off < 64; off <<= 1) {
        float m2 = __shfl_xor(m, off);
        float s2 = __shfl_xor(s, off);
        int   c2 = __shfl_xor(cc, off);
        float nm = fmaxf(m, m2);
        s = s * __expf(m - nm) + s2 * __expf(m2 - nm);
        if (m2 > m || (m2 == m && c2 < cc)) cc = c2;
        m = nm;
    }
    __shared__ float smM[4], smS[4]; __shared__ int smC[4];
    if ((t & 63) == 0) { smM[t>>6] = m; smS[t>>6] = s; smC[t>>6] = cc; }
    __syncthreads();
    if (t == 0) {
        m = smM[0]; s = smS[0]; cc = smC[0];
        for (int i = 1; i < 4; i++) {
            float m2 = smM[i], s2 = smS[i]; int c2 = smC[i];
            float nm = fmaxf(m, m2);
            s = s * __expf(m - nm) + s2 * __expf(m2 - nm);
            if (m2 > m || (m2 == m && c2 < cc)) cc = c2;
            m = nm;
        }
        token[row] = cc;
        tok_logp[row] = -__logf(s);
    }
}

__global__ __launch_bounds__(256) void dot_gather_kernel(
    const float* __restrict__ rx, const float* __restrict__ rw,
    const int* __restrict__ token, float* __restrict__ out)
{
    int row = blockIdx.x, t = threadIdx.x;
    const float4* a = (const float4*)(rx + (size_t)row * H_DIM);
    const float4* b = (const float4*)(rw + (size_t)token[row] * H_DIM);
    float4 a0 = a[t*2], a1 = a[t*2+1], b0 = b[t*2], b1 = b[t*2+1];
    float s = a0.x*b0.x + a0.y*b0.y + a0.z*b0.z + a0.w*b0.w
            + a1.x*b1.x + a1.y*b1.y + a1.z*b1.z + a1.w*b1.w;
    for (int off = 1; off < 64; off <<= 1) s += __shfl_xor(s, off);
    __shared__ float ss[4];
    if ((t & 63) == 0) ss[t >> 6] = s;
    __syncthreads();
    if (t == 0) out[row] = ss[0] + ss[1] + ss[2] + ss[3];
}

__global__ __launch_bounds__(256) void reduce_ref_kernel(
    const float4* __restrict__ part, const float* __restrict__ tok_logp,
    const float* __restrict__ gathered, float* __restrict__ klrow, int nblk)
{
    int row = blockIdx.x, t = threadIdx.x;
    float m = -3.0e38f, s = 0.f;
    if (t < nblk) { float4 p = part[(size_t)row * nblk + t]; m = p.x; s = p.y; }
    for (int off = 1; off < 64; off <<= 1) {
        float m2 = __shfl_xor(m, off), s2 = __shfl_xor(s, off);
        merge_ms(m, s, m2, s2);
    }
    __shared__ float smM[4], smS[4];
    if ((t & 63) == 0) { smM[t>>6] = m; smS[t>>6] = s; }
    __syncthreads();
    if (t == 0) {
        m = smM[0]; s = smS[0];
        for (int i = 1; i < 4; i++) merge_ms(m, s, smM[i], smS[i]);
        float lse = m + __logf(s);
        float d = (gathered[row] - lse) - tok_logp[row];
        klrow[row] = __expf(d) - d - 1.0f;
    }
}

__global__ __launch_bounds__(256) void final_kernel(
    const int* __restrict__ amask, const float* __restrict__ rewards,
    const float* __restrict__ klrow, float* __restrict__ out)
{
    int t = threadIdx.x;
    int b = t >> 5;
    int g = b >> 2;
    float r0 = rewards[g*4+0], r1 = rewards[g*4+1], r2 = rewards[g*4+2], r3 = rewards[g*4+3];
    float mean = 0.25f * (r0 + r1 + r2 + r3);
    float var = ((r0-mean)*(r0-mean) + (r1-mean)*(r1-mean) +
                 (r2-mean)*(r2-mean) + (r3-mean)*(r3-mean)) * (1.0f/3.0f);  // ddof=1
    float adv = (rewards[b] - mean) / (sqrtf(var) + EPSR);

    float ln = 0.f, ms = 0.f, kb = 0.f, mb = 0.f;
    for (int i = 0; i < 8; i++) {
        int row = t*8 + i;
        float mk = (float)amask[row];
        float kl = klrow[row];
        ln += (adv - BETA * kl) * mk;
        ms += mk;
        kb += kl * mk;
        mb += mk;
    }
    __shared__ float sLN[256], sMS[256], sKB[256], sMB[256], sKLb[8];
    sLN[t] = ln; sMS[t] = ms; sKB[t] = kb; sMB[t] = mb;
    __syncthreads();
    if (t < 8) {
        float skb = 0.f, smb = 0.f;
        for (int i = 0; i < 32; i++) { skb += sKB[t*32+i]; smb += sMB[t*32+i]; }
        sKLb[t] = skb / smb;
    }
    __syncthreads();
    if (t == 0) {
        float lnt = 0.f, mst = 0.f;
        for (int i = 0; i < 256; i++) { lnt += sLN[i]; mst += sMS[i]; }
        float mkl = 0.f;
        for (int i = 0; i < 8; i++) mkl += sKLb[i];
        out[0] = -lnt / mst;
        out[1] = mkl * 0.125f;
    }
}

// ---------------- launch ----------------

extern "C" void kernel_launch(void* const* d_in, const int* in_sizes, int n_in,
                              void* d_out, int out_size, void* d_ws, size_t ws_size,
                              hipStream_t stream)
{
    const float* x       = (const float*)d_in[0];
    const float* w       = (const float*)d_in[1];
    const int*   amask   = (const int*)  d_in[2];
    const float* rewards = (const float*)d_in[3];
    const float* rx      = (const float*)d_in[4];
    const float* rw      = (const float*)d_in[5];
    float* out = (float*)d_out;
    char* ws = (char*)d_ws;

    const size_t W_P  = (size_t)V_DIM * H_DIM * 2;   // 131,072,000 bf16 bytes (ONE buffer)
    const size_t A_P  = (size_t)BT * H_DIM * 2;      //   8,388,608
    const size_t PART = (size_t)BT * NBLK2 * 16;     //   4,096,000
    const size_t NEED = W_P + 2*A_P + 2*PART + 32768;   // 156 MB

    if (ws_size >= NEED) {
        // ---- fast path (R7 structure, best measured 1078 us): shared weight slab buffer
        // packed twice (w, then rw after gemm1 -- stream order serializes, no race).
        ushort* Wp   = (ushort*)(ws);                 // shared slab buffer (w, then rw)
        ushort* Ap   = (ushort*)(ws + W_P);
        ushort* Rp   = (ushort*)(ws + W_P + A_P);
        float4* part  = (float4*)(ws + W_P + 2*A_P);
        float4* part2 = (float4*)(ws + W_P + 2*A_P + PART);
        char*   tail  =          ws + W_P + 2*A_P + 2*PART;
        float* klrow    = (float*)(tail);

        pack_act_kernel<<<dim3(256),  512, 0, stream>>>(x, rx, (uint4*)Ap, (uint4*)Rp);
        pack_w_kernel  <<<dim3(2000), 512, 0, stream>>>(w, (uint4*)Wp);

        gemm_lse_v7<<<dim3(1000), 512, 0, stream>>>(Ap, Wp, part);    // policy

        pack_w_kernel  <<<dim3(2000), 512, 0, stream>>>(rw, (uint4*)Wp);

        gemm_lse_v7<<<dim3(1000), 512, 0, stream>>>(Rp, Wp, part2);   // reference

        row_tail_kernel<<<BT, 256, 0, stream>>>(part, part2, rx, rw, klrow);
        final_kernel<<<1, 256, 0, stream>>>(amask, rewards, klrow, out);
    } else {
        // ---- fallback: round-1 path (ws too small for packed weights) ----
        const size_t PART_FB = (size_t)BT * NBLK_FB * 16;
        float4* part     = (float4*)ws;
        int*    token    = (int*)  (ws + PART_FB);
        float*  tok_logp = (float*)(ws + PART_FB + 8192);
        float*  gathered = (float*)(ws + PART_FB + 16384);
        float*  klrow    = (float*)(ws + PART_FB + 24576);

        dim3 g(BT / TM, NBLK_FB), blk(256);
        gemm_lse_fallback<<<g, blk, 0, stream>>>(x, w, part, nullptr, nullptr);
        reduce_policy_kernel<<<BT, 256, 0, stream>>>(part, token, tok_logp, NBLK_FB);
        gemm_lse_fallback<<<g, blk, 0, stream>>>(rx, rw, part, token, gathered);
        reduce_ref_kernel<<<BT, 256, 0, stream>>>(part, tok_logp, gathered, klrow, NBLK_FB);
        final_kernel<<<1, 256, 0, stream>>>(amask, rewards, klrow, out);
    }
}